// Round 10
// baseline (94.450 us; speedup 1.0000x reference)
//
#include <hip/hip_runtime.h>
#include <cstdint>
#include <cstddef>

// Problem constants (fixed by setup_inputs)
#define ZSEQ 8
#define NSEQ 2048
#define NH 4
#define DH 128
#define QKV_STRIDE (NH * 3 * DH) /* 1536 floats per token row */
#define OUT_STRIDE (NH * DH)     /* 512 floats per token row */
#define ALPHA 0.08838834764831843f
#define LOG2E 1.4426950408889634f
#define QSCALE (ALPHA * LOG2E)                 /* fold log2e into Q */
#define VSCALE (1.0f / (2048.0f * LOG2E))      /* fold 1/(2048*log2e) into V */
#define TILE_B 16384             /* bytes per 64-row K tile / per V tile */

typedef _Float16 h8 __attribute__((ext_vector_type(8)));
typedef __fp16 fp16x2 __attribute__((ext_vector_type(2)));
typedef float fx16 __attribute__((ext_vector_type(16)));
typedef unsigned int ui4v __attribute__((ext_vector_type(4)));
typedef unsigned short u16t;

// global_load_lds: per-lane global src, wave-uniform LDS base (HW adds lane*16)
#define GLDS(gp, lp)                                                        \
  __builtin_amdgcn_global_load_lds(                                         \
      (__attribute__((address_space(1))) void*)(gp),                        \
      (__attribute__((address_space(3))) void*)(lp), 16, 0, 0)

__device__ __forceinline__ h8 cvt8(float4 a, float4 b) {
  h8 r;
  r[0] = (_Float16)a.x; r[1] = (_Float16)a.y; r[2] = (_Float16)a.z; r[3] = (_Float16)a.w;
  r[4] = (_Float16)b.x; r[5] = (_Float16)b.y; r[6] = (_Float16)b.z; r[7] = (_Float16)b.w;
  return r;
}

__device__ __forceinline__ unsigned pku(float a, float b) {
  union { fp16x2 h; unsigned u; } c;
  c.h = __builtin_amdgcn_cvt_pkrtz(a, b);
  return c.u;
}

// ---------------------------------------------------------------------------
// Prep: qkv f32 -> pre-swizzled f16 tiles in d_ws.
//   K tiles: [zh][nt][64 rows x 256B], byte col c stored at c ^ ((row&7)<<4)
//   V tiles: [zh][nt][128 d-rows x 128B], col c stored at c ^ ((d&7)<<4)
//   V values pre-scaled by VSCALE (silu exp2/2048 folding).
//   V tile COLUMN ORDER is bit2<->bit3 swapped in n (pi(c) = swap bits 2,3):
//   column c holds V row n0 + pi(c). This matches the natural per-lane order
//   of S^T fragments after swapped-QK^T MFMA, so PV needs NO cross-lane ops.
// ---------------------------------------------------------------------------
__global__ __launch_bounds__(256) void prep_kernel(const float* __restrict__ qkv,
                                                   const int* __restrict__ seq_offsets,
                                                   char* __restrict__ k16,
                                                   char* __restrict__ vt) {
  __shared__ u16t Vl[64 * 136];  // padded transpose staging
  const int t = threadIdx.x;
  const int b = blockIdx.x;
  const int z = b >> 7;
  const int h = (b >> 5) & 3;
  const int nb = b & 31;
  const int n0 = nb * 64;
  const int start = seq_offsets[z];
  const int zh = z * NH + h;
  const size_t tb = (size_t)(zh * 32 + nb) * TILE_B;

#pragma unroll
  for (int i = 0; i < 2; ++i) {
    const int r = i * 32 + (t >> 3);
    const int c16 = (t & 7) * 16;  // element col
    const int cb = c16 * 2;        // byte col
    const float* src = qkv + (size_t)(start + n0 + r) * QKV_STRIDE + h * (3 * DH);
    // ---- K (swizzled) ----
    float4 a0 = *(const float4*)(src + DH + c16);
    float4 a1 = *(const float4*)(src + DH + c16 + 4);
    float4 a2 = *(const float4*)(src + DH + c16 + 8);
    float4 a3 = *(const float4*)(src + DH + c16 + 12);
    char* kd = k16 + tb + r * 256;
    *(h8*)(kd + (cb ^ ((r & 7) << 4))) = cvt8(a0, a1);
    *(h8*)(kd + ((cb + 16) ^ ((r & 7) << 4))) = cvt8(a2, a3);
    // ---- V -> LDS (row-major, padded), pre-scaled by VSCALE ----
    float4 v0 = *(const float4*)(src + 2 * DH + c16);
    float4 v1 = *(const float4*)(src + 2 * DH + c16 + 4);
    float4 v2 = *(const float4*)(src + 2 * DH + c16 + 8);
    float4 v3 = *(const float4*)(src + 2 * DH + c16 + 12);
    v0.x *= VSCALE; v0.y *= VSCALE; v0.z *= VSCALE; v0.w *= VSCALE;
    v1.x *= VSCALE; v1.y *= VSCALE; v1.z *= VSCALE; v1.w *= VSCALE;
    v2.x *= VSCALE; v2.y *= VSCALE; v2.z *= VSCALE; v2.w *= VSCALE;
    v3.x *= VSCALE; v3.y *= VSCALE; v3.z *= VSCALE; v3.w *= VSCALE;
    *(h8*)((char*)Vl + r * 272 + cb) = cvt8(v0, v1);
    *(h8*)((char*)Vl + r * 272 + cb + 16) = cvt8(v2, v3);
  }
  __syncthreads();
  // transpose out: V tile rows = d, cols = n with pi (bits 2,3 of n swapped)
#pragma unroll
  for (int j = 0; j < 2; ++j) {
    const int d = j * 64 + (t >> 2);
    const int n16 = (t & 3) * 16;
    const int cn = n16 * 2;  // byte col of this 16-col group
    h8 o0, o1;
#pragma unroll
    for (int k2 = 0; k2 < 8; ++k2) {
      const int r0 = (k2 & 3) + 8 * (k2 >> 2);
      o0[k2] = *(const _Float16*)((const char*)Vl + (n16 + r0) * 272 + d * 2);
      o1[k2] = *(const _Float16*)((const char*)Vl + (n16 + 4 + r0) * 272 + d * 2);
    }
    char* vd = vt + tb + d * 128;
    *(h8*)(vd + (cn ^ ((d & 7) << 4))) = o0;
    *(h8*)(vd + ((cn + 16) ^ ((d & 7) << 4))) = o1;
  }
}

// silu + causal mask on one S^T accumulator (in place).
// s holds s2 = (alpha*log2e) * q.k; silu_ref/2048 = VSCALE * s2*rcp(1+2^-s2),
// with VSCALE folded into V. s element i at n = n0+nbase+(i&3)+8*(i>>2)+4*lh.
__device__ __forceinline__ void silu_mask(fx16& s, int nbase, bool needmask, int n0,
                                          int mrow, int lh) {
#pragma unroll
  for (int i = 0; i < 16; ++i) {
    const float sv = s[i];
    const float e2 = __builtin_amdgcn_exp2f(-sv);
    float sil = sv * __builtin_amdgcn_rcpf(1.0f + e2);
    if (needmask && (n0 + nbase + (i & 3) + 8 * (i >> 2) + 4 * lh > mrow)) sil = 0.0f;
    s[i] = sil;
  }
}

// pack 8 consecutive s elements (b = 0 or 8) into an f16 A-fragment.
__device__ __forceinline__ h8 pack8(const fx16& s, int b) {
  union { ui4v u; h8 h; } cv;
  cv.u = (ui4v){pku(s[b + 0], s[b + 1]), pku(s[b + 2], s[b + 3]),
                pku(s[b + 4], s[b + 5]), pku(s[b + 6], s[b + 7])};
  return cv.h;
}

// ---------------------------------------------------------------------------
// Attention r10 = r8 structure + T3/T4 pipelining: 256 blocks = 32 zh x 8
// folds, 4 waves, BM=128, KV tile 64. TRIPLE-buffered K/V (96KB = 64KB static
// + 32KB dynamic, 1 block/CU). Stage tile j+2 at END of iter j; top of iter
// waits counted `s_waitcnt vmcnt(8)` (only stage(j+1)'s 8 GLDS/wave may stay
// in flight) + raw s_barrier -- NO vmcnt(0) drain in the loop. Tail iters
// issue dummy re-stages to keep the outstanding count uniform.
// Fold: block f computes m-tile f (2f+2 kv-tiles) then 15-f (32-2f): 34 iters
// for every block. Inner loop identical to verified r4..r9.
// ---------------------------------------------------------------------------
__global__ __launch_bounds__(256, 1) void attn_kernel(const float* __restrict__ qkv,
                                                      const int* __restrict__ seq_offsets,
                                                      const char* __restrict__ k16,
                                                      const char* __restrict__ vt,
                                                      float* __restrict__ out) {
  __shared__ u16t KV01[2][16384];     // buffers 0,1: K at [0..8191], V at [8192..]
  extern __shared__ u16t KV2[];       // buffer 2 (32KB dynamic), same layout

  const int t = threadIdx.x;
  const int lane = t & 63;
  const int w = t >> 6;
  const int l31 = lane & 31;
  const int lh = lane >> 5;

  const int bid = blockIdx.x;
  const int f = bid >> 5;        // fold 0..7
  const int zh = bid & 31;
  const int z = zh >> 2;
  const int h = zh & 3;
  const int start = seq_offsets[z];
  const size_t tbase = (size_t)(zh * 32) * TILE_B;
  const int spanA = 2 * f + 2;   // iters for phase A (m-tile f); total = 34

  int mt = f;
  int wm0 = mt * 128 + w * 32;
  int mrow = wm0 + l31;

  h8 qf[8];
  fx16 oacc[4];

  auto kbuf = [&](int b) -> u16t* { return (b < 2) ? &KV01[b][0] : &KV2[0]; };
  auto vbuf = [&](int b) -> u16t* { return (b < 2) ? &KV01[b][8192] : &KV2[8192]; };

  auto loadQ = [&]() {
    const float* qrow = qkv + (size_t)(start + mrow) * QKV_STRIDE + h * (3 * DH);
#pragma unroll
    for (int ks = 0; ks < 8; ++ks) {
      const int d0 = ks * 16 + lh * 8;
      float4 a = *(const float4*)(qrow + d0);
      float4 b = *(const float4*)(qrow + d0 + 4);
      a.x *= QSCALE; a.y *= QSCALE; a.z *= QSCALE; a.w *= QSCALE;
      b.x *= QSCALE; b.y *= QSCALE; b.z *= QSCALE; b.w *= QSCALE;
      qf[ks] = cvt8(a, b);
    }
  };
  auto zeroAcc = [&]() {
#pragma unroll
    for (int db = 0; db < 4; ++db)
#pragma unroll
      for (int i = 0; i < 16; ++i) oacc[db][i] = 0.0f;
  };
  auto flushAcc = [&]() {
#pragma unroll
    for (int db = 0; db < 4; ++db) {
      const int d = db * 32 + l31;
#pragma unroll
      for (int i = 0; i < 16; ++i) {
        const int m = wm0 + (i & 3) + 8 * (i >> 2) + 4 * lh;
        out[(size_t)(start + m) * OUT_STRIDE + h * DH + d] = oacc[db][i];
      }
    }
  };
  // stage kv-tile kt2 into buffer bsel: 8 GLDS per wave (4 K + 4 V)
  auto stage = [&](int bsel, int kt2) {
    const char* kg = k16 + tbase + (size_t)kt2 * TILE_B + w * 4096 + lane * 16;
    const char* vg = vt + tbase + (size_t)kt2 * TILE_B + w * 4096 + lane * 16;
    u16t* kl = kbuf(bsel) + w * 2048;
    u16t* vl = vbuf(bsel) + w * 2048;
#pragma unroll
    for (int i = 0; i < 4; ++i) {
      GLDS(kg + i * 1024, kl + i * 512);
      GLDS(vg + i * 1024, vl + i * 512);
    }
  };
  // tile index for pipeline slot j (dummy-clamped at tail)
  auto tileOf = [&](int j) {
    int jj = (j > 33) ? 33 : j;
    return (jj < spanA) ? jj : jj - spanA;
  };

  loadQ();
  zeroAcc();
  stage(0, tileOf(0));
  stage(1, tileOf(1));

  for (int j = 0; j < 34; ++j) {
    if (j == spanA) {  // phase switch: flush tile-f output, move to tile 15-f
      flushAcc();
      mt = 15 - f;
      wm0 = mt * 128 + w * 32;
      mrow = wm0 + l31;
      loadQ();
      zeroAcc();
    }
    const int cb3 = j % 3;
    // wait until only stage(j+1)'s 8 GLDS may remain in flight => stage(j) done
    asm volatile("s_waitcnt vmcnt(8)" ::: "memory");
    __builtin_amdgcn_sched_barrier(0);
    __builtin_amdgcn_s_barrier();  // all waves' stage(j) landed

    const int kt = tileOf(j);
    const int n0 = kt * 64;
    {
      const char* kb = (const char*)kbuf(cb3);
      const char* vb = (const char*)vbuf(cb3);

      // ---- batch ALL 16 K-fragment reads (independent -> pipelined) ----
      h8 a0[8], a1[8];
      const int sw = (l31 & 7) << 4;
#pragma unroll
      for (int ks = 0; ks < 8; ++ks) {
        const int cb = 32 * ks + 16 * lh;
        a0[ks] = *(const h8*)(kb + l31 * 256 + (cb ^ sw));
        a1[ks] = *(const h8*)(kb + (32 + l31) * 256 + (cb ^ sw));
      }
      // ---- S^T = K Q^T ----
      fx16 s0, s1;
#pragma unroll
      for (int i = 0; i < 16; ++i) { s0[i] = 0.0f; s1[i] = 0.0f; }
      __builtin_amdgcn_s_setprio(1);
#pragma unroll
      for (int ks = 0; ks < 8; ++ks) {
        s0 = __builtin_amdgcn_mfma_f32_32x32x16_f16(a0[ks], qf[ks], s0, 0, 0, 0);
        s1 = __builtin_amdgcn_mfma_f32_32x32x16_f16(a1[ks], qf[ks], s1, 0, 0, 0);
      }
      __builtin_amdgcn_s_setprio(0);

      // ---- batch ALL 16 V-fragment reads; silu VALU hides their latency ----
      h8 bv[4][4];
#pragma unroll
      for (int ks = 0; ks < 4; ++ks) {
        const int cb = 32 * ks + 16 * lh;
#pragma unroll
        for (int db = 0; db < 4; ++db) {
          const int rr = db * 32 + l31;
          bv[ks][db] = *(const h8*)(vb + rr * 128 + (cb ^ ((rr & 7) << 4)));
        }
      }
      // ---- silu + mask (in-register), pack to PV A-fragments ----
      const bool needmask = (n0 + 63 > wm0);
      silu_mask(s0, 0, needmask, n0, mrow, lh);
      silu_mask(s1, 32, needmask, n0, mrow, lh);
      h8 pa[4];
      pa[0] = pack8(s0, 0);
      pa[1] = pack8(s0, 8);
      pa[2] = pack8(s1, 0);
      pa[3] = pack8(s1, 8);
      // ---- O += P V ----
      __builtin_amdgcn_s_setprio(1);
#pragma unroll
      for (int ks = 0; ks < 4; ++ks) {
#pragma unroll
        for (int db = 0; db < 4; ++db) {
          oacc[db] = __builtin_amdgcn_mfma_f32_32x32x16_f16(pa[ks], bv[ks][db], oacc[db], 0, 0, 0);
        }
      }
      __builtin_amdgcn_s_setprio(0);
    }
    __builtin_amdgcn_s_barrier();  // all waves done reading buf cb3
    stage((j + 2) % 3, tileOf(j + 2));  // prefetch depth 2 (dummy at tail)
  }
  flushAcc();  // phase B epilogue
}

// ---------------------------------------------------------------------------
// Never-expected fallback (ws too small): naive per-(token,head) block.
// ---------------------------------------------------------------------------
__global__ __launch_bounds__(128) void fallback_kernel(const float* __restrict__ qkv,
                                                       const int* __restrict__ seq_offsets,
                                                       float* __restrict__ out) {
  const int token = blockIdx.x;
  const int h = blockIdx.y;
  const int z = token >> 11;
  const int m = token & 2047;
  const int start = seq_offsets[z];
  const int t = threadIdx.x;  // = d
  const float qd = qkv[(size_t)(start + m) * QKV_STRIDE + h * (3 * DH) + t] * ALPHA;
  __shared__ float red[2];
  float acc = 0.0f;
  for (int n = 0; n <= m; ++n) {
    const float kd = qkv[(size_t)(start + n) * QKV_STRIDE + h * (3 * DH) + DH + t];
    float part = qd * kd;
#pragma unroll
    for (int o = 32; o; o >>= 1) part += __shfl_down(part, o);
    if ((t & 63) == 0) red[t >> 6] = part;
    __syncthreads();
    const float s = red[0] + red[1];
    const float sil = s / ((1.0f + __expf(-s)) * 2048.0f);
    acc += sil * qkv[(size_t)(start + n) * QKV_STRIDE + h * (3 * DH) + 2 * DH + t];
    __syncthreads();
  }
  out[(size_t)(start + m) * OUT_STRIDE + h * DH + t] = acc;
}

// ---------------------------------------------------------------------------
extern "C" void kernel_launch(void* const* d_in, const int* in_sizes, int n_in,
                              void* d_out, int out_size, void* d_ws, size_t ws_size,
                              hipStream_t stream) {
  (void)in_sizes; (void)n_in; (void)out_size;
  const float* qkv = (const float*)d_in[0];
  const int* seq_offsets = (const int*)d_in[1];
  // d_in[2..4] (timestamps, ts_weights, pos_weights) unused by the reference.
  float* out = (float*)d_out;

  const size_t half = (size_t)ZSEQ * NH * 32 * TILE_B;  // 16 MiB (bytes)

  if (ws_size >= 2 * half) {
    char* k16 = (char*)d_ws;
    char* vt = k16 + half;
    prep_kernel<<<ZSEQ * NH * (NSEQ / 64), 256, 0, stream>>>(qkv, seq_offsets, k16, vt);
    // 32KB dynamic LDS = third K/V buffer; 96KB total -> 1 block/CU.
    attn_kernel<<<ZSEQ * NH * 8, 256, 32768, stream>>>(qkv, seq_offsets, k16, vt, out);
  } else {
    fallback_kernel<<<dim3(ZSEQ * NSEQ, NH), 128, 0, stream>>>(qkv, seq_offsets, out);
  }
}